// Round 1
// baseline (455.462 us; speedup 1.0000x reference)
//
#include <hip/hip_runtime.h>

// ---------------------------------------------------------------------------
// Fused attention: context = softmax((q@Wq+bq)(k@Wk+bk)^T / 32) @ (v@Wv+bv)
// S=4096, H=D=1024, fp32 in/out, bf16 MFMA internally.
//
// ws layout (MB offsets):
//   0: Wt_q bf16 [1024][1024]   (2 MB)
//   2: Wt_k bf16                (2 MB)
//   4: Wt_v bf16                (2 MB)
//   6: Q  bf16 [4096][1024]     (8 MB)
//  14: K  bf16 [4096][1024]     (8 MB)
//  22: V  bf16 [4096][1024]     (8 MB)
//  30: Vt bf16 [1024][4096]     (8 MB)
//  38: S  fp32 [4096][4096]     (64 MB)   -> softmaxed in place (P)
// total 102 MB
// ---------------------------------------------------------------------------

typedef short short8 __attribute__((ext_vector_type(8)));
typedef float f32x4  __attribute__((ext_vector_type(4)));

#define MFMA16 __builtin_amdgcn_mfma_f32_16x16x32_bf16

__device__ __forceinline__ short f2bf(float f) {
    union { float f; unsigned u; } x; x.f = f;
    unsigned r = (x.u + 0x7FFFu + ((x.u >> 16) & 1u)) >> 16;  // RNE
    return (short)r;
}

__device__ __forceinline__ void store_out(short* p, float v) { *p = f2bf(v); }
__device__ __forceinline__ void store_out(float* p, float v) { *p = v; }

// --- transpose+cast the three weight matrices: W[k][n] fp32 -> T[n][k] bf16 --
__global__ __launch_bounds__(256) void prep_w(
    const float* __restrict__ W0, const float* __restrict__ W1,
    const float* __restrict__ W2,
    short* __restrict__ T0, short* __restrict__ T1, short* __restrict__ T2)
{
    __shared__ float tile[64][65];
    const float* W = blockIdx.z == 0 ? W0 : (blockIdx.z == 1 ? W1 : W2);
    short*       T = blockIdx.z == 0 ? T0 : (blockIdx.z == 1 ? T1 : T2);
    const int c0 = blockIdx.x * 64;           // N dim of W
    const int r0 = blockIdx.y * 64;           // K dim of W
    const int tx = threadIdx.x & 63;
    const int ty = threadIdx.x >> 6;          // 0..3
    #pragma unroll
    for (int p = 0; p < 16; ++p) {
        int r = ty + p * 4;
        tile[r][tx] = W[(size_t)(r0 + r) * 1024 + c0 + tx];
    }
    __syncthreads();
    #pragma unroll
    for (int p = 0; p < 16; ++p) {
        int r = ty + p * 4;
        T[(size_t)(c0 + r) * 1024 + r0 + tx] = f2bf(tile[tx][r]);
    }
}

// --- bf16 transpose: in[R][C] -> out[C][R] -------------------------------
__global__ __launch_bounds__(256) void transpose_bf16(
    const short* __restrict__ in, short* __restrict__ out, int R, int C)
{
    __shared__ short tile[64][66];
    const int c0 = blockIdx.x * 64;
    const int r0 = blockIdx.y * 64;
    const int tx = threadIdx.x & 63;
    const int ty = threadIdx.x >> 6;
    #pragma unroll
    for (int p = 0; p < 16; ++p) {
        int r = ty + p * 4;
        tile[r][tx] = in[(size_t)(r0 + r) * C + c0 + tx];
    }
    __syncthreads();
    #pragma unroll
    for (int p = 0; p < 16; ++p) {
        int r = ty + p * 4;
        out[(size_t)(c0 + r) * R + r0 + tx] = tile[tx][r];
    }
}

// --- C[M][N] = scale * (A[M][Kd] @ Bt[N][Kd]^T) + bias -------------------
// A: fp32 (cast to bf16 while staging) or bf16-as-short. Bt: bf16-as-short.
// 128x128 block tile, BK=32, 256 threads = 4 waves of 64, each wave 64x64.
template <typename TA, typename TOut, bool BIAS>
__global__ __launch_bounds__(256) void gemm_bt(
    const TA* __restrict__ A, const short* __restrict__ Bt,
    const float* __restrict__ bias, TOut* __restrict__ C,
    int M, int N, int Kd, float scale)
{
    __shared__ short As[128][40];   // +8 pad: conflict-free b128 frag reads
    __shared__ short Bs[128][40];

    const int t  = threadIdx.x;
    const int n0 = blockIdx.x * 128;
    const int m0 = blockIdx.y * 128;

    const int lane = t & 63;
    const int wv   = t >> 6;
    const int wm   = wv & 1;          // wave tile row
    const int wn   = wv >> 1;         // wave tile col
    const int lr   = lane & 15;
    const int lq   = lane >> 4;

    const int srow = t >> 1;          // staging row 0..127
    const int scol = (t & 1) * 16;    // 0 or 16

    f32x4 acc[4][4];
    #pragma unroll
    for (int i = 0; i < 4; ++i)
        #pragma unroll
        for (int j = 0; j < 4; ++j) {
            f32x4 z = {0.f, 0.f, 0.f, 0.f};
            acc[i][j] = z;
        }

    const int niter = Kd >> 5;
    for (int kk = 0; kk < niter; ++kk) {
        const int k0 = kk << 5;
        // stage A (convert fp32->bf16 if needed)
        {
            const TA* ap = A + (size_t)(m0 + srow) * Kd + k0 + scol;
            short8 p0, p1;
            if constexpr (sizeof(TA) == 4) {
                const float4* a4 = (const float4*)ap;
                float4 g0 = a4[0], g1 = a4[1], g2 = a4[2], g3 = a4[3];
                p0[0] = f2bf(g0.x); p0[1] = f2bf(g0.y); p0[2] = f2bf(g0.z); p0[3] = f2bf(g0.w);
                p0[4] = f2bf(g1.x); p0[5] = f2bf(g1.y); p0[6] = f2bf(g1.z); p0[7] = f2bf(g1.w);
                p1[0] = f2bf(g2.x); p1[1] = f2bf(g2.y); p1[2] = f2bf(g2.z); p1[3] = f2bf(g2.w);
                p1[4] = f2bf(g3.x); p1[5] = f2bf(g3.y); p1[6] = f2bf(g3.z); p1[7] = f2bf(g3.w);
            } else {
                p0 = *(const short8*)ap;
                p1 = *(const short8*)(ap + 8);
            }
            *(short8*)&As[srow][scol]     = p0;
            *(short8*)&As[srow][scol + 8] = p1;
        }
        // stage B (always bf16)
        {
            const short* bp = Bt + (size_t)(n0 + srow) * Kd + k0 + scol;
            *(short8*)&Bs[srow][scol]     = *(const short8*)bp;
            *(short8*)&Bs[srow][scol + 8] = *(const short8*)(bp + 8);
        }
        __syncthreads();

        short8 af[4], bf[4];
        #pragma unroll
        for (int i = 0; i < 4; ++i)
            af[i] = *(const short8*)&As[wm * 64 + i * 16 + lr][lq * 8];
        #pragma unroll
        for (int j = 0; j < 4; ++j)
            bf[j] = *(const short8*)&Bs[wn * 64 + j * 16 + lr][lq * 8];
        #pragma unroll
        for (int i = 0; i < 4; ++i)
            #pragma unroll
            for (int j = 0; j < 4; ++j)
                acc[i][j] = MFMA16(af[i], bf[j], acc[i][j], 0, 0, 0);
        __syncthreads();
    }

    // epilogue: C/D layout col=lane&15, row=(lane>>4)*4+reg (m89/m91 verified)
    #pragma unroll
    for (int i = 0; i < 4; ++i) {
        #pragma unroll
        for (int j = 0; j < 4; ++j) {
            const int crow = m0 + wm * 64 + i * 16 + lq * 4;
            const int ccol = n0 + wn * 64 + j * 16 + lr;
            float bb = 0.f;
            if constexpr (BIAS) bb = bias[ccol];
            #pragma unroll
            for (int r = 0; r < 4; ++r) {
                float val = acc[i][j][r] * scale + bb;
                store_out(&C[(size_t)(crow + r) * N + ccol], val);
            }
        }
    }
}

// --- row softmax in place over S[4096][4096] ------------------------------
__global__ __launch_bounds__(256) void softmax_inplace(float* __restrict__ S)
{
    const int row = blockIdx.x;
    float* r = S + (size_t)row * 4096;
    const int t = threadIdx.x;
    float4* r4 = (float4*)r;

    float x[16];
    #pragma unroll
    for (int i = 0; i < 4; ++i) {
        float4 f = r4[t + 256 * i];
        x[4 * i + 0] = f.x; x[4 * i + 1] = f.y;
        x[4 * i + 2] = f.z; x[4 * i + 3] = f.w;
    }
    float m = -1e30f;
    #pragma unroll
    for (int i = 0; i < 16; ++i) m = fmaxf(m, x[i]);
    #pragma unroll
    for (int off = 32; off > 0; off >>= 1) m = fmaxf(m, __shfl_xor(m, off));

    __shared__ float redm[4], reds[4];
    const int wv = t >> 6;
    if ((t & 63) == 0) redm[wv] = m;
    __syncthreads();
    m = fmaxf(fmaxf(redm[0], redm[1]), fmaxf(redm[2], redm[3]));

    float s = 0.f;
    #pragma unroll
    for (int i = 0; i < 16; ++i) { x[i] = __expf(x[i] - m); s += x[i]; }
    #pragma unroll
    for (int off = 32; off > 0; off >>= 1) s += __shfl_xor(s, off);
    if ((t & 63) == 0) reds[wv] = s;
    __syncthreads();
    s = reds[0] + reds[1] + reds[2] + reds[3];
    const float inv = 1.f / s;

    #pragma unroll
    for (int i = 0; i < 4; ++i) {
        float4 f;
        f.x = x[4 * i + 0] * inv; f.y = x[4 * i + 1] * inv;
        f.z = x[4 * i + 2] * inv; f.w = x[4 * i + 3] * inv;
        r4[t + 256 * i] = f;
    }
}

extern "C" void kernel_launch(void* const* d_in, const int* in_sizes, int n_in,
                              void* d_out, int out_size, void* d_ws, size_t ws_size,
                              hipStream_t stream)
{
    const float* q     = (const float*)d_in[0];
    const float* k     = (const float*)d_in[1];
    const float* v     = (const float*)d_in[2];
    const float* Wq    = (const float*)d_in[3];
    const float* bq    = (const float*)d_in[4];
    const float* Wk    = (const float*)d_in[5];
    const float* bk    = (const float*)d_in[6];
    const float* Wv    = (const float*)d_in[7];
    const float* bv_in = (const float*)d_in[8];
    float* out = (float*)d_out;

    char* ws = (char*)d_ws;
    const size_t MB = 1ull << 20;
    short* Wtq = (short*)(ws + 0 * MB);
    short* Wtk = (short*)(ws + 2 * MB);
    short* Wtv = (short*)(ws + 4 * MB);
    short* Qb  = (short*)(ws + 6 * MB);
    short* Kb  = (short*)(ws + 14 * MB);
    short* Vb  = (short*)(ws + 22 * MB);
    short* Vtb = (short*)(ws + 30 * MB);
    float* S   = (float*)(ws + 38 * MB);

    // 1) W^T casts
    prep_w<<<dim3(16, 16, 3), 256, 0, stream>>>(Wq, Wk, Wv, Wtq, Wtk, Wtv);
    // 2) projections -> bf16
    gemm_bt<float, short, true><<<dim3(8, 32), 256, 0, stream>>>(q, Wtq, bq, Qb, 4096, 1024, 1024, 1.f);
    gemm_bt<float, short, true><<<dim3(8, 32), 256, 0, stream>>>(k, Wtk, bk, Kb, 4096, 1024, 1024, 1.f);
    gemm_bt<float, short, true><<<dim3(8, 32), 256, 0, stream>>>(v, Wtv, bv_in, Vb, 4096, 1024, 1024, 1.f);
    // 3) V^T for the PV gemm
    transpose_bf16<<<dim3(16, 64), 256, 0, stream>>>(Vb, Vtb, 4096, 1024);
    // 4) S = Q K^T / 32
    gemm_bt<short, float, false><<<dim3(32, 32), 256, 0, stream>>>(Qb, Kb, nullptr, S, 4096, 4096, 1024, 0.03125f);
    // 5) softmax rows in place
    softmax_inplace<<<4096, 256, 0, stream>>>(S);
    // 6) out = P @ V
    gemm_bt<float, float, false><<<dim3(8, 32), 256, 0, stream>>>(S, Vtb, nullptr, out, 4096, 1024, 4096, 1.f);
}

// Round 2
// 293.282 us; speedup vs baseline: 1.5530x; 1.5530x over previous
//
#include <hip/hip_runtime.h>

// ---------------------------------------------------------------------------
// context = softmax((q@Wq+bq)(k@Wk+bk)^T / 32) @ (v@Wv+bv)
// S=4096, H=D=1024. fp32 in/out, bf16 MFMA internally, m97-style GEMMs
// (global_load_lds width-16 staging, 128x128 tile, BK=32, XOR chunk swizzle).
//
// ws layout (byte offsets, MB):
//   [ 0, 6)  Wt  bf16 [3][1024][1024]  (W^T, transposed+cast)
//   [ 6,30)  xb  bf16 [3][4096][1024]  (q,k,v cast)
//   [30,54)  pr  bf16 [3][4096][1024]  (Q,K,V projections)
//   [54,62)  Vt  bf16 [1024][4096]
//   [62,94)  S   bf16 [4096][4096]     (scores -> softmaxed in place)
//   [ 0,34)  p0/p1 fp32 partials       (reuses dead Wt/xb/pr region at PV time)
// ---------------------------------------------------------------------------

typedef short short4v __attribute__((ext_vector_type(4)));
typedef short short8  __attribute__((ext_vector_type(8)));
typedef float f32x4   __attribute__((ext_vector_type(4)));

#define MFMA16 __builtin_amdgcn_mfma_f32_16x16x32_bf16

__device__ __forceinline__ short f2bf(float f) {
    union { float f; unsigned u; } x; x.f = f;
    unsigned r = (x.u + 0x7FFFu + ((x.u >> 16) & 1u)) >> 16;  // RNE
    return (short)r;
}
__device__ __forceinline__ float bf2f(short s) {
    union { unsigned u; float f; } x;
    x.u = ((unsigned)(unsigned short)s) << 16; return x.f;
}
__device__ __forceinline__ void store_out(short* p, float v) { *p = f2bf(v); }
__device__ __forceinline__ void store_out(float* p, float v) { *p = v; }

// async global->LDS, 16B per lane. LDS dest = wave-uniform base + lane*16.
__device__ __forceinline__ void gl2lds(const short* g, short* l) {
    __builtin_amdgcn_global_load_lds(
        (const __attribute__((address_space(1))) void*)g,
        (__attribute__((address_space(3))) void*)l, 16, 0, 0);
}

// --- W[k][n] fp32 -> Wt[z][n][k] bf16 ------------------------------------
__global__ __launch_bounds__(256) void prep_w(
    const float* __restrict__ W0, const float* __restrict__ W1,
    const float* __restrict__ W2, short* __restrict__ Wt)
{
    __shared__ float tile[64][65];
    const float* W = blockIdx.z == 0 ? W0 : (blockIdx.z == 1 ? W1 : W2);
    short* T = Wt + (size_t)blockIdx.z * 1048576;
    const int c0 = blockIdx.x * 64;
    const int r0 = blockIdx.y * 64;
    const int tx = threadIdx.x & 63;
    const int ty = threadIdx.x >> 6;
    #pragma unroll
    for (int p = 0; p < 16; ++p) {
        int r = ty + p * 4;
        tile[r][tx] = W[(size_t)(r0 + r) * 1024 + c0 + tx];
    }
    __syncthreads();
    #pragma unroll
    for (int p = 0; p < 16; ++p) {
        int r = ty + p * 4;
        T[(size_t)(c0 + r) * 1024 + r0 + tx] = f2bf(tile[tx][r]);
    }
}

// --- q,k,v fp32 -> xb bf16 -----------------------------------------------
__global__ __launch_bounds__(256) void cast_qkv(
    const float* __restrict__ q, const float* __restrict__ k,
    const float* __restrict__ v, short* __restrict__ xb)
{
    const float* src = blockIdx.z == 0 ? q : (blockIdx.z == 1 ? k : v);
    short* dst = xb + (size_t)blockIdx.z * 4194304;
    for (int i = blockIdx.x * 256 + threadIdx.x; i < 1048576; i += 256 * 1024) {
        float4 f = ((const float4*)src)[i];
        short4v o;
        o[0] = f2bf(f.x); o[1] = f2bf(f.y); o[2] = f2bf(f.z); o[3] = f2bf(f.w);
        ((short4v*)dst)[i] = o;
    }
}

// --- bf16 transpose: in[R][C] -> out[C][R] -------------------------------
__global__ __launch_bounds__(256) void transpose_bf16(
    const short* __restrict__ in, short* __restrict__ out, int R, int C)
{
    __shared__ short tile[64][66];
    const int c0 = blockIdx.x * 64;
    const int r0 = blockIdx.y * 64;
    const int tx = threadIdx.x & 63;
    const int ty = threadIdx.x >> 6;
    #pragma unroll
    for (int p = 0; p < 16; ++p) {
        int r = ty + p * 4;
        tile[r][tx] = in[(size_t)(r0 + r) * C + c0 + tx];
    }
    __syncthreads();
    #pragma unroll
    for (int p = 0; p < 16; ++p) {
        int r = ty + p * 4;
        out[(size_t)(c0 + r) * R + r0 + tx] = tile[tx][r];
    }
}

// --- m97-style bf16 GEMM: C = scale*(A @ Bt^T) [+ bias] -------------------
// A[M][lda] bf16, Bt[N][ldb] bf16. 128x128 tile, BK=32, 4 waves, 4x4 frags.
// MODE 0: plain. MODE 1: blockIdx.z selects {A,Bt,C,bias} triple (projections).
// MODE 2: blockIdx.z is split-K index (kbeg = z*kiters*32, C += z*M*N).
template <typename TOut, int MODE>
__global__ __launch_bounds__(256) void gemm_lds(
    const short* __restrict__ A, const short* __restrict__ Bt,
    const float* __restrict__ b0, const float* __restrict__ b1,
    const float* __restrict__ b2, TOut* __restrict__ C,
    int M, int N, int Kd, int lda, int ldb, float scale, int kiters)
{
    __shared__ short As[128 * 32];   // unpadded: required by global_load_lds
    __shared__ short Bs[128 * 32];

    const int t    = threadIdx.x;
    const int lane = t & 63;
    const int wv   = t >> 6;
    const int n0 = blockIdx.x * 128;
    const int m0 = blockIdx.y * 128;

    const float* bias = nullptr;
    int kbeg = 0;
    if constexpr (MODE == 1) {
        const int z = blockIdx.z;
        A  += (size_t)z * M * lda;
        Bt += (size_t)z * N * ldb;
        C  += (size_t)z * M * N;
        bias = z == 0 ? b0 : (z == 1 ? b1 : b2);
    }
    if constexpr (MODE == 2) {
        kbeg = blockIdx.z * kiters * 32;
        C += (size_t)blockIdx.z * M * N;
    }
    (void)b0; (void)b1; (void)b2;

    // staging: wave w, round r covers LDS bytes [(w*2+r)*1024, +1024).
    // lane l -> row = w*32 + r*16 + (l>>2), stored chunk c_s = l&3 (16B chunks).
    // XOR swizzle: stored chunk c_s holds logical chunk c_s ^ ((row>>2)&3);
    // for this mapping key = (l>>4)&3 (independent of w,r).
    const int srow = wv * 32 + (lane >> 2);
    const int cl   = ((lane & 3) ^ ((lane >> 4) & 3)) * 8;  // element offset
    const short* pA0 = A  + (size_t)(m0 + srow) * lda + kbeg + cl;
    const short* pA1 = pA0 + (size_t)16 * lda;
    const short* pB0 = Bt + (size_t)(n0 + srow) * ldb + kbeg + cl;
    const short* pB1 = pB0 + (size_t)16 * ldb;
    short* lA0 = &As[(wv * 2 + 0) * 512];
    short* lA1 = &As[(wv * 2 + 1) * 512];
    short* lB0 = &Bs[(wv * 2 + 0) * 512];
    short* lB1 = &Bs[(wv * 2 + 1) * 512];

    const int wm = wv & 1, wn = wv >> 1;
    const int lr = lane & 15, lq = lane >> 4;
    const int swz = ((lq ^ ((lr >> 2) & 3))) * 8;  // read-side swizzled chunk

    f32x4 acc[4][4];
    #pragma unroll
    for (int i = 0; i < 4; ++i)
        #pragma unroll
        for (int j = 0; j < 4; ++j) {
            f32x4 z = {0.f, 0.f, 0.f, 0.f};
            acc[i][j] = z;
        }

    for (int kk = 0; kk < kiters; ++kk) {
        gl2lds(pA0, lA0); gl2lds(pA1, lA1);
        gl2lds(pB0, lB0); gl2lds(pB1, lB1);
        pA0 += 32; pA1 += 32; pB0 += 32; pB1 += 32;
        __syncthreads();   // drains vmcnt(0): global_load_lds complete

        short8 af[4], bfr[4];
        #pragma unroll
        for (int i = 0; i < 4; ++i)
            af[i] = *(const short8*)&As[(wm * 64 + i * 16 + lr) * 32 + swz];
        #pragma unroll
        for (int j = 0; j < 4; ++j)
            bfr[j] = *(const short8*)&Bs[(wn * 64 + j * 16 + lr) * 32 + swz];
        #pragma unroll
        for (int i = 0; i < 4; ++i)
            #pragma unroll
            for (int j = 0; j < 4; ++j)
                acc[i][j] = MFMA16(af[i], bfr[j], acc[i][j], 0, 0, 0);
        __syncthreads();
    }

    // epilogue: C/D layout col=lane&15, row=(lane>>4)*4+reg (m89/m91)
    #pragma unroll
    for (int i = 0; i < 4; ++i) {
        #pragma unroll
        for (int j = 0; j < 4; ++j) {
            const int crow = m0 + wm * 64 + i * 16 + lq * 4;
            const int ccol = n0 + wn * 64 + j * 16 + lr;
            float bb = 0.f;
            if constexpr (MODE == 1) bb = bias[ccol];
            #pragma unroll
            for (int r = 0; r < 4; ++r) {
                float val = acc[i][j][r] * scale + bb;
                store_out(&C[(size_t)(crow + r) * N + ccol], val);
            }
        }
    }
}

// --- row softmax in place over bf16 S[4096][4096] -------------------------
__global__ __launch_bounds__(256) void softmax_bf16(short* __restrict__ S)
{
    const int row = blockIdx.x;
    short8* r8 = (short8*)(S + (size_t)row * 4096);
    const int t = threadIdx.x;

    float x[16];
    #pragma unroll
    for (int i = 0; i < 2; ++i) {
        short8 raw = r8[t + 256 * i];
        #pragma unroll
        for (int j = 0; j < 8; ++j) x[8 * i + j] = bf2f(raw[j]);
    }
    float m = -1e30f;
    #pragma unroll
    for (int i = 0; i < 16; ++i) m = fmaxf(m, x[i]);
    #pragma unroll
    for (int off = 32; off > 0; off >>= 1) m = fmaxf(m, __shfl_xor(m, off));

    __shared__ float redm[4], reds[4];
    const int wv = t >> 6;
    if ((t & 63) == 0) redm[wv] = m;
    __syncthreads();
    m = fmaxf(fmaxf(redm[0], redm[1]), fmaxf(redm[2], redm[3]));

    float s = 0.f;
    #pragma unroll
    for (int i = 0; i < 16; ++i) { x[i] = __expf(x[i] - m); s += x[i]; }
    #pragma unroll
    for (int off = 32; off > 0; off >>= 1) s += __shfl_xor(s, off);
    if ((t & 63) == 0) reds[wv] = s;
    __syncthreads();
    s = reds[0] + reds[1] + reds[2] + reds[3];
    const float inv = 1.f / s;

    #pragma unroll
    for (int i = 0; i < 2; ++i) {
        short8 o;
        #pragma unroll
        for (int j = 0; j < 8; ++j) o[j] = f2bf(x[8 * i + j] * inv);
        r8[t + 256 * i] = o;
    }
}

// --- out = p0 + p1 (split-K combine) --------------------------------------
__global__ __launch_bounds__(256) void combine(
    const float* __restrict__ p0, const float* __restrict__ p1,
    float* __restrict__ out)
{
    for (int i = blockIdx.x * 256 + threadIdx.x; i < 1048576; i += 256 * 1024) {
        float4 a = ((const float4*)p0)[i];
        float4 b = ((const float4*)p1)[i];
        float4 o; o.x = a.x + b.x; o.y = a.y + b.y;
        o.z = a.z + b.z; o.w = a.w + b.w;
        ((float4*)out)[i] = o;
    }
}

extern "C" void kernel_launch(void* const* d_in, const int* in_sizes, int n_in,
                              void* d_out, int out_size, void* d_ws, size_t ws_size,
                              hipStream_t stream)
{
    const float* q  = (const float*)d_in[0];
    const float* k  = (const float*)d_in[1];
    const float* v  = (const float*)d_in[2];
    const float* Wq = (const float*)d_in[3];
    const float* bq = (const float*)d_in[4];
    const float* Wk = (const float*)d_in[5];
    const float* bk = (const float*)d_in[6];
    const float* Wv = (const float*)d_in[7];
    const float* bv = (const float*)d_in[8];
    float* out = (float*)d_out;

    char* ws = (char*)d_ws;
    const size_t MB = 1ull << 20;
    short* Wt = (short*)(ws + 0);        // 3 x 1M shorts
    short* xb = (short*)(ws + 6 * MB);   // 3 x 4M shorts
    short* pr = (short*)(ws + 30 * MB);  // 3 x 4M shorts
    short* Vt = (short*)(ws + 54 * MB);  // 4M shorts
    short* S  = (short*)(ws + 62 * MB);  // 16M shorts
    float* p0 = (float*)(ws + 0);        // 2 x 4M floats (dead region at PV time)
    float* p1 = p0 + 4194304;

    // 1) W^T + cast, q/k/v cast
    prep_w<<<dim3(16, 16, 3), 256, 0, stream>>>(Wq, Wk, Wv, Wt);
    cast_qkv<<<dim3(1024, 1, 3), 256, 0, stream>>>(q, k, v, xb);
    // 2) fused projections: pr[z] = xb[z] @ Wt[z]^T + b[z]   (768 blocks)
    gemm_lds<short, 1><<<dim3(8, 32, 3), 256, 0, stream>>>(
        xb, Wt, bq, bk, bv, pr, 4096, 1024, 1024, 1024, 1024, 1.f, 32);
    // 3) V^T
    transpose_bf16<<<dim3(16, 64), 256, 0, stream>>>(pr + 2 * 4194304, Vt, 4096, 1024);
    // 4) S = Q K^T / 32  (bf16 out, 1024 blocks)
    gemm_lds<short, 0><<<dim3(32, 32), 256, 0, stream>>>(
        pr, pr + 4194304, nullptr, nullptr, nullptr, S,
        4096, 4096, 1024, 1024, 1024, 0.03125f, 32);
    // 5) softmax rows in place (bf16)
    softmax_bf16<<<4096, 256, 0, stream>>>(S);
    // 6) partials = P @ V  (split-K=2, 512 blocks)
    gemm_lds<float, 2><<<dim3(8, 32, 2), 256, 0, stream>>>(
        S, Vt, nullptr, nullptr, nullptr, p0,
        4096, 1024, 4096, 4096, 4096, 1.f, 64);
    // 7) out = p0 + p1
    combine<<<1024, 256, 0, stream>>>(p0, p1, out);
}

// Round 3
// 267.983 us; speedup vs baseline: 1.6996x; 1.0944x over previous
//
#include <hip/hip_runtime.h>

// ---------------------------------------------------------------------------
// context = softmax((q@Wq+bq)(k@Wk+bk)^T / 32) @ (v@Wv+bv)
// S=4096, H=D=1024. fp32 in/out, bf16 MFMA internally.
// GEMM core: 128x128 tile, BK=64 (32 KB LDS), global_load_lds width-16,
// XOR-8 chunk swizzle (2-way bank aliasing = free), band-swizzled grid.
//
// ws layout (MB):
//   [ 0, 6)  Wt  bf16 [3][1024][1024]
//   [ 6,30)  xb  bf16 [3][4096][1024]   (q,k,v cast)
//   [30,46)  pr  bf16 [2][4096][1024]   (Q,K projections)
//   [46,54)  Vt  bf16 [1024][4096]      (written by V-projection epilogue)
//   [54,86)  S   bf16 [4096][4096]      (scores -> softmaxed in place)
//   [ 0,32)  p0/p1 fp32 partials        (reuses dead Wt/xb region at PV time)
// ---------------------------------------------------------------------------

typedef short short4v __attribute__((ext_vector_type(4)));
typedef short short8  __attribute__((ext_vector_type(8)));
typedef float f32x4   __attribute__((ext_vector_type(4)));

#define MFMA16 __builtin_amdgcn_mfma_f32_16x16x32_bf16

__device__ __forceinline__ short f2bf(float f) {
    union { float f; unsigned u; } x; x.f = f;
    unsigned r = (x.u + 0x7FFFu + ((x.u >> 16) & 1u)) >> 16;  // RNE
    return (short)r;
}
__device__ __forceinline__ float bf2f(short s) {
    union { unsigned u; float f; } x;
    x.u = ((unsigned)(unsigned short)s) << 16; return x.f;
}
__device__ __forceinline__ void store_out(short* p, float v) { *p = f2bf(v); }
__device__ __forceinline__ void store_out(float* p, float v) { *p = v; }

// async global->LDS, 16B/lane. LDS dest = wave-uniform base + lane*16.
__device__ __forceinline__ void gl2lds(const short* g, short* l) {
    __builtin_amdgcn_global_load_lds(
        (const __attribute__((address_space(1))) void*)g,
        (__attribute__((address_space(3))) void*)l, 16, 0, 0);
}

// --- W[k][n] fp32 -> Wt[z][n][k] bf16 ------------------------------------
__global__ __launch_bounds__(256) void prep_w(
    const float* __restrict__ W0, const float* __restrict__ W1,
    const float* __restrict__ W2, short* __restrict__ Wt)
{
    __shared__ float tile[64][65];
    const float* W = blockIdx.z == 0 ? W0 : (blockIdx.z == 1 ? W1 : W2);
    short* T = Wt + (size_t)blockIdx.z * 1048576;
    const int c0 = blockIdx.x * 64;
    const int r0 = blockIdx.y * 64;
    const int tx = threadIdx.x & 63;
    const int ty = threadIdx.x >> 6;
    #pragma unroll
    for (int p = 0; p < 16; ++p) {
        int r = ty + p * 4;
        tile[r][tx] = W[(size_t)(r0 + r) * 1024 + c0 + tx];
    }
    __syncthreads();
    #pragma unroll
    for (int p = 0; p < 16; ++p) {
        int r = ty + p * 4;
        T[(size_t)(c0 + r) * 1024 + r0 + tx] = f2bf(tile[tx][r]);
    }
}

// --- q,k,v fp32 -> xb bf16 -----------------------------------------------
__global__ __launch_bounds__(256) void cast_qkv(
    const float* __restrict__ q, const float* __restrict__ k,
    const float* __restrict__ v, short* __restrict__ xb)
{
    const float* src = blockIdx.z == 0 ? q : (blockIdx.z == 1 ? k : v);
    short* dst = xb + (size_t)blockIdx.z * 4194304;
    for (int i = blockIdx.x * 256 + threadIdx.x; i < 1048576; i += 256 * 1024) {
        float4 f = ((const float4*)src)[i];
        short4v o;
        o[0] = f2bf(f.x); o[1] = f2bf(f.y); o[2] = f2bf(f.z); o[3] = f2bf(f.w);
        ((short4v*)dst)[i] = o;
    }
}

// --- bf16 GEMM core: C = scale*(A @ Bt^T) [+ bias] ------------------------
// 128x128 tile, BK=64, 4 waves, 4x4 16x16x32 frags per wave, 2 K-halves.
// MODE 0: plain. MODE 1: z selects {A,Bt,C,bias}; z==2 writes Vt (transposed)
// instead of C. MODE 2: z is split-K index (kbeg=z*kiters*64, C += z*M*N).
template <typename TOut, int MODE>
__global__ __launch_bounds__(256) void gemm64(
    const short* __restrict__ A, const short* __restrict__ Bt,
    const float* __restrict__ b0, const float* __restrict__ b1,
    const float* __restrict__ b2, TOut* __restrict__ C,
    short* __restrict__ Vt,
    int M, int N, int Kd, int lda, int ldb, float scale, int kiters)
{
    constexpr int LDSN = (MODE == 1) ? (128 * 136) : (128 * 64 * 2);
    __shared__ short Lds[LDSN];
    short* As = Lds;                  // [128][64]
    short* Bs = Lds + 128 * 64;       // [128][64]

    const int t    = threadIdx.x;
    const int lane = t & 63;
    const int wv   = t >> 6;

    // band-swizzled grid: 8 m-tiles per band; each XCD keeps an A-panel hot
    const int nb  = gridDim.x;
    const int bid = blockIdx.y * nb + blockIdx.x;
    const int band   = bid / (8 * nb);
    const int within = bid - band * 8 * nb;
    const int m0 = (band * 8 + (within & 7)) * 128;
    const int n0 = (within >> 3) * 128;

    const float* bias = nullptr;
    int kbeg = 0;
    if constexpr (MODE == 1) {
        const int z = blockIdx.z;
        A  += (size_t)z * M * lda;
        Bt += (size_t)z * N * ldb;
        C  += (size_t)z * M * N;
        bias = z == 0 ? b0 : (z == 1 ? b1 : b2);
    }
    if constexpr (MODE == 2) {
        kbeg = blockIdx.z * kiters * 64;
        C += (size_t)blockIdx.z * M * N;
    }
    (void)b0; (void)b1; (void)b2;

    // staging: wave w stages rows [w*32, w*32+32) of both tiles, 4 rounds.
    // round r, lane l -> row = w*32 + r*8 + (l>>3), stored 16B-chunk = l&7
    // holding logical chunk (l&7)^(l>>3)  (XOR-8 swizzle, key = row&7).
    const int sr = lane >> 3;                 // 0..7
    const int sc = (lane & 7) ^ sr;           // logical chunk this lane loads
    const short* pA = A  + (size_t)(m0 + wv * 32 + sr) * lda + kbeg + sc * 8;
    const short* pB = Bt + (size_t)(n0 + wv * 32 + sr) * ldb + kbeg + sc * 8;
    const size_t a8 = (size_t)8 * lda;
    const size_t b8 = (size_t)8 * ldb;
    short* lA = As + wv * 2048;               // wave base (row w*32)
    short* lB = Bs + wv * 2048;

    const int wm = wv & 1, wn = wv >> 1;
    const int lr = lane & 15, lq = lane >> 4;
    const int xkey = lr & 7;                  // read-side XOR key

    f32x4 acc[4][4];
    #pragma unroll
    for (int i = 0; i < 4; ++i)
        #pragma unroll
        for (int j = 0; j < 4; ++j) {
            f32x4 z = {0.f, 0.f, 0.f, 0.f};
            acc[i][j] = z;
        }

    for (int kk = 0; kk < kiters; ++kk) {
        #pragma unroll
        for (int r = 0; r < 4; ++r) gl2lds(pA + r * a8, lA + r * 512);
        #pragma unroll
        for (int r = 0; r < 4; ++r) gl2lds(pB + r * b8, lB + r * 512);
        pA += 64; pB += 64;
        __syncthreads();   // drains vmcnt(0): staging complete

        #pragma unroll
        for (int h = 0; h < 2; ++h) {
            short8 af[4], bfr[4];
            #pragma unroll
            for (int i = 0; i < 4; ++i)
                af[i] = *(const short8*)
                    &As[(wm * 64 + i * 16 + lr) * 64 + (((h * 4 + lq) ^ xkey) * 8)];
            #pragma unroll
            for (int j = 0; j < 4; ++j)
                bfr[j] = *(const short8*)
                    &Bs[(wn * 64 + j * 16 + lr) * 64 + (((h * 4 + lq) ^ xkey) * 8)];
            #pragma unroll
            for (int i = 0; i < 4; ++i)
                #pragma unroll
                for (int j = 0; j < 4; ++j)
                    acc[i][j] = MFMA16(af[i], bfr[j], acc[i][j], 0, 0, 0);
        }
        __syncthreads();
    }

    // ---- epilogue -----------------------------------------------------
    if constexpr (MODE == 1) {
        if (blockIdx.z == 2) {
            // V-projection: transpose tile through LDS, write Vt[1024][4096]
            #pragma unroll
            for (int i = 0; i < 4; ++i) {
                #pragma unroll
                for (int j = 0; j < 4; ++j) {
                    const int colL = wn * 64 + j * 16 + lr;
                    const float bb = bias[n0 + colL];
                    #pragma unroll
                    for (int r = 0; r < 4; ++r) {
                        const int rowL = wm * 64 + i * 16 + lq * 4 + r;
                        Lds[colL * 136 + rowL] = f2bf(acc[i][j][r] * scale + bb);
                    }
                }
            }
            __syncthreads();
            const int c = t >> 1, part = t & 1;
            short* dst = Vt + (size_t)(n0 + c) * 4096 + m0 + part * 64;
            #pragma unroll
            for (int s = 0; s < 8; ++s)
                *(short8*)(dst + s * 8) =
                    *(const short8*)&Lds[c * 136 + part * 64 + s * 8];
            return;
        }
    }
    // standard epilogue: C/D layout col=lane&15, row=(lane>>4)*4+reg
    #pragma unroll
    for (int i = 0; i < 4; ++i) {
        #pragma unroll
        for (int j = 0; j < 4; ++j) {
            const int crow = m0 + wm * 64 + i * 16 + lq * 4;
            const int ccol = n0 + wn * 64 + j * 16 + lr;
            float bb = 0.f;
            if constexpr (MODE == 1) bb = bias[ccol];
            #pragma unroll
            for (int r = 0; r < 4; ++r) {
                float val = acc[i][j][r] * scale + bb;
                store_out(&C[(size_t)(crow + r) * N + ccol], val);
            }
        }
    }
}

// --- row softmax in place over bf16 S[4096][4096] -------------------------
__global__ __launch_bounds__(256) void softmax_bf16(short* __restrict__ S)
{
    const int row = blockIdx.x;
    short8* r8 = (short8*)(S + (size_t)row * 4096);
    const int t = threadIdx.x;

    float x[16];
    #pragma unroll
    for (int i = 0; i < 2; ++i) {
        short8 raw = r8[t + 256 * i];
        #pragma unroll
        for (int j = 0; j < 8; ++j) x[8 * i + j] = bf2f(raw[j]);
    }
    float m = -1e30f;
    #pragma unroll
    for (int i = 0; i < 16; ++i) m = fmaxf(m, x[i]);
    #pragma unroll
    for (int off = 32; off > 0; off >>= 1) m = fmaxf(m, __shfl_xor(m, off));

    __shared__ float redm[4], reds[4];
    const int wv = t >> 6;
    if ((t & 63) == 0) redm[wv] = m;
    __syncthreads();
    m = fmaxf(fmaxf(redm[0], redm[1]), fmaxf(redm[2], redm[3]));

    float s = 0.f;
    #pragma unroll
    for (int i = 0; i < 16; ++i) { x[i] = __expf(x[i] - m); s += x[i]; }
    #pragma unroll
    for (int off = 32; off > 0; off >>= 1) s += __shfl_xor(s, off);
    if ((t & 63) == 0) reds[wv] = s;
    __syncthreads();
    s = reds[0] + reds[1] + reds[2] + reds[3];
    const float inv = 1.f / s;

    #pragma unroll
    for (int i = 0; i < 2; ++i) {
        short8 o;
        #pragma unroll
        for (int j = 0; j < 8; ++j) o[j] = f2bf(x[8 * i + j] * inv);
        r8[t + 256 * i] = o;
    }
}

// --- out = p0 + p1 (split-K combine) --------------------------------------
__global__ __launch_bounds__(256) void combine(
    const float* __restrict__ p0, const float* __restrict__ p1,
    float* __restrict__ out)
{
    for (int i = blockIdx.x * 256 + threadIdx.x; i < 1048576; i += 256 * 1024) {
        float4 a = ((const float4*)p0)[i];
        float4 b = ((const float4*)p1)[i];
        float4 o; o.x = a.x + b.x; o.y = a.y + b.y;
        o.z = a.z + b.z; o.w = a.w + b.w;
        ((float4*)out)[i] = o;
    }
}

extern "C" void kernel_launch(void* const* d_in, const int* in_sizes, int n_in,
                              void* d_out, int out_size, void* d_ws, size_t ws_size,
                              hipStream_t stream)
{
    const float* q  = (const float*)d_in[0];
    const float* k  = (const float*)d_in[1];
    const float* v  = (const float*)d_in[2];
    const float* Wq = (const float*)d_in[3];
    const float* bq = (const float*)d_in[4];
    const float* Wk = (const float*)d_in[5];
    const float* bk = (const float*)d_in[6];
    const float* Wv = (const float*)d_in[7];
    const float* bv = (const float*)d_in[8];
    float* out = (float*)d_out;

    char* ws = (char*)d_ws;
    const size_t MB = 1ull << 20;
    short* Wt = (short*)(ws + 0);         // 3 x 1M shorts
    short* xb = (short*)(ws + 6 * MB);    // 3 x 4M shorts
    short* pr = (short*)(ws + 30 * MB);   // 2 x 4M shorts (Q,K)
    short* Vt = (short*)(ws + 46 * MB);   // 4M shorts
    short* S  = (short*)(ws + 54 * MB);   // 16M shorts
    float* p0 = (float*)(ws + 0);         // 2 x 4M floats (dead region by then)
    float* p1 = p0 + 4194304;

    // 1) W^T + cast, q/k/v cast
    prep_w<<<dim3(16, 16, 3), 256, 0, stream>>>(Wq, Wk, Wv, Wt);
    cast_qkv<<<dim3(1024, 1, 3), 256, 0, stream>>>(q, k, v, xb);
    // 2) projections: Q,K -> pr; V -> Vt (transposed in epilogue)
    gemm64<short, 1><<<dim3(8, 32, 3), 256, 0, stream>>>(
        xb, Wt, bq, bk, bv, pr, Vt, 4096, 1024, 1024, 1024, 1024, 1.f, 16);
    // 3) S = Q K^T / 32
    gemm64<short, 0><<<dim3(32, 32), 256, 0, stream>>>(
        pr, pr + 4194304, nullptr, nullptr, nullptr, S, nullptr,
        4096, 4096, 1024, 1024, 1024, 0.03125f, 16);
    // 4) softmax rows in place (bf16)
    softmax_bf16<<<4096, 256, 0, stream>>>(S);
    // 5) partials = P @ V  (split-K=2)
    gemm64<float, 2><<<dim3(8, 32, 2), 256, 0, stream>>>(
        S, Vt, nullptr, nullptr, nullptr, p0, nullptr,
        4096, 1024, 4096, 4096, 4096, 1.f, 32);
    // 6) out = p0 + p1
    combine<<<1024, 256, 0, stream>>>(p0, p1, out);
}